// Round 4
// baseline (226.896 us; speedup 1.0000x reference)
//
#include <hip/hip_runtime.h>

// Problem constants: B=4, K=16, H=480, W=640, P=200000, C=3
constexpr int B_ = 4, K_ = 16, H_ = 480, W_ = 640, P_ = 200000;
constexpr int HW = H_ * W_;    // 307200 pixels per (b,k) plane
constexpr int HP = HW / 2;     // two pixels per thread: p and p+HP

typedef unsigned int u32;

// Pre-pass: ptclds (3,P) f32 -> (P) x 3x10-bit fixed-point in [-6,6], one
// u32 per point (800 KB table). Step 12/1023 ~= 0.0117 -> weighted error
// <= 0.006 (weights sum to <=1), well under the 9.2e-2 threshold.
__global__ __launch_bounds__(256) void build_table(
    const float* __restrict__ ptclds, u32* __restrict__ tab)
{
    const int i = blockIdx.x * 256 + threadIdx.x;
    if (i < P_) {
        auto q = [](float v) -> u32 {
            float x = (v + 6.f) * (1023.f / 12.f);
            x = fminf(fmaxf(x, 0.f), 1023.f);
            return (u32)(x + 0.5f);
        };
        tab[i] = q(ptclds[i]) | (q(ptclds[P_ + i]) << 10)
               | (q(ptclds[2 * P_ + i]) << 20);
    }
}

// R10: regime-discriminating round. R7/R8/R9 post-mortems: compiler refuses
// to keep >~8 stream loads in flight (VGPR 64/100/52) -> stream-MLP lever
// is dead. New theory: the floor is the serial chain
//   stream -> 16-step weight chain -> gathers -> decode
// with the high-latency divergent gathers at the END. The gather index
// depends only on fi (not w), so this round hoists ALL 32 gathers,
// unconditional (clamped index; dummy decode killed by w==0 -> numerics
// identical to R7), issued straight after the fi loads and BEFORE the
// weight chain:  fi -> gathers || (ai -> weights) -> decode.
// Single variable vs R7 (same px layout, same nt streams, same EPS):
// gather placement+speculation. (256,3) for the extra ~32 live pk regs.
// Pre-committed read: dur ~42 => serialization was the floor;
// dur >=65 => line-processing-bound -> next round cuts gather lines.
__global__ __launch_bounds__(256, 3) void compositor_kernel(
    const int*   __restrict__ frag,    // (B,K,H,W) int32
    const float* __restrict__ alpha,   // (B,K,H,W) f32
    const u32*   __restrict__ tab,     // (P) packed 3x10-bit table
    const float* __restrict__ im,      // (3,H,W) f32
    float*       __restrict__ out)     // (B,3,H,W) f32
{
    const int t = blockIdx.x * blockDim.x + threadIdx.x;   // [0, B_*HP)
    const int b  = t / HP;
    const int p0 = t - b * HP;     // [0, HW/2)
    const int p1 = p0 + HP;

    const int*   fb = frag  + (size_t)b * K_ * HW;
    const float* ab = alpha + (size_t)b * K_ * HW;

    // 1) fragment stream loads first (gather addresses depend on these)
    int fi0[K_], fi1[K_];
    #pragma unroll
    for (int k = 0; k < K_; ++k) {
        fi0[k] = __builtin_nontemporal_load(fb + (size_t)k * HW + p0);
        fi1[k] = __builtin_nontemporal_load(fb + (size_t)k * HW + p1);
    }
    // 2) alpha stream loads issued behind them (fly during the fi wait)
    float ai0[K_], ai1[K_];
    #pragma unroll
    for (int k = 0; k < K_; ++k) {
        ai0[k] = __builtin_nontemporal_load(ab + (size_t)k * HW + p0);
        ai1[k] = __builtin_nontemporal_load(ab + (size_t)k * HW + p1);
    }

    // 3) ALL 32 gathers, unconditional, clamped index. Issued as soon as
    //    fi values land; overlap the alpha drain + weight chain. Regular
    //    (cached) loads: table must stay L2-hot.
    u32 pk0[K_], pk1[K_];
    #pragma unroll
    for (int k = 0; k < K_; ++k) {
        pk0[k] = tab[fi0[k] >= 0 ? fi0[k] : 0];
        pk1[k] = tab[fi1[k] >= 0 ? fi1[k] : 0];
    }
    // fence: gathers must NOT sink into the decode (that recreates the
    // serial chain this round exists to break)
    __builtin_amdgcn_sched_barrier(0);

    // 4) weights — pure VALU (bg skip + low-weight skip, EPS as R7)
    constexpr float EPS = 2.5e-3f;
    const bool bg0 = fi0[0] < 0;
    const bool bg1 = fi1[0] < 0;
    float w0[K_], w1[K_];
    {
        float T0 = 1.f, T1 = 1.f;
        #pragma unroll
        for (int k = 0; k < K_; ++k) {
            const float a0 = fi0[k] >= 0 ? ai0[k] : 0.0f;
            const float a1 = fi1[k] >= 0 ? ai1[k] : 0.0f;
            const float wk0 = a0 * T0;  T0 *= (1.0f - a0);
            const float wk1 = a1 * T1;  T1 *= (1.0f - a1);
            w0[k] = (!bg0 && wk0 > EPS) ? wk0 : 0.0f;
            w1[k] = (!bg1 && wk1 > EPS) ? wk1 : 0.0f;
        }
    }

    // 5) decode + accumulate (speculated values for w==0 lanes are
    //    multiplied by 0 -> exact, same numerics as R7)
    constexpr float S = 12.f / 1023.f;
    float r0 = 0.f, g0 = 0.f, b0 = 0.f;
    float r1 = 0.f, g1 = 0.f, b1 = 0.f;
    #pragma unroll
    for (int k = 0; k < K_; ++k) {
        r0 += w0[k] * ((float)( pk0[k]        & 1023u) * S - 6.f);
        g0 += w0[k] * ((float)((pk0[k] >> 10) & 1023u) * S - 6.f);
        b0 += w0[k] * ((float)((pk0[k] >> 20) & 1023u) * S - 6.f);
        r1 += w1[k] * ((float)( pk1[k]        & 1023u) * S - 6.f);
        g1 += w1[k] * ((float)((pk1[k] >> 10) & 1023u) * S - 6.f);
        b1 += w1[k] * ((float)((pk1[k] >> 20) & 1023u) * S - 6.f);
    }

    // 6) background override + non-temporal coalesced stores
    const size_t ob = (size_t)b * 3 * HW;
    const float o00 = bg0 ? im[p0]          : r0;
    const float o01 = bg0 ? im[HW + p0]     : g0;
    const float o02 = bg0 ? im[2 * HW + p0] : b0;
    const float o10 = bg1 ? im[p1]          : r1;
    const float o11 = bg1 ? im[HW + p1]     : g1;
    const float o12 = bg1 ? im[2 * HW + p1] : b1;
    __builtin_nontemporal_store(o00, out + ob + p0);
    __builtin_nontemporal_store(o01, out + ob + HW + p0);
    __builtin_nontemporal_store(o02, out + ob + 2 * HW + p0);
    __builtin_nontemporal_store(o10, out + ob + p1);
    __builtin_nontemporal_store(o11, out + ob + HW + p1);
    __builtin_nontemporal_store(o12, out + ob + 2 * HW + p1);
}

extern "C" void kernel_launch(void* const* d_in, const int* in_sizes, int n_in,
                              void* d_out, int out_size, void* d_ws, size_t ws_size,
                              hipStream_t stream) {
    const int*   frag   = (const int*)  d_in[0];
    const float* alpha  = (const float*)d_in[1];
    const float* ptclds = (const float*)d_in[2];
    const float* im     = (const float*)d_in[3];
    float*       out    = (float*)d_out;

    u32* tab = (u32*)d_ws;  // 800 KB < ws_size
    build_table<<<(P_ + 255) / 256, 256, 0, stream>>>(ptclds, tab);

    const int total_threads = B_ * HP;   // 614,400 (2 px/thread)
    compositor_kernel<<<total_threads / 256, 256, 0, stream>>>(
        frag, alpha, tab, im, out);
}

// Round 5
// 199.365 us; speedup vs baseline: 1.1381x; 1.1381x over previous
//
#include <hip/hip_runtime.h>

// Problem constants: B=4, K=16, H=480, W=640, P=200000, C=3
constexpr int B_ = 4, K_ = 16, H_ = 480, W_ = 640, P_ = 200000;
constexpr int HW = H_ * W_;    // 307200 pixels per (b,k) plane

typedef unsigned int u32;

// Pre-pass: ptclds (3,P) f32 -> (P) x 3x10-bit fixed-point in [-6,6], one
// u32 per point (800 KB table). Step 12/1023 ~= 0.0117 -> weighted error
// <= 0.006 (weights sum to <=1), well under the 9.2e-2 threshold.
__global__ __launch_bounds__(256) void build_table(
    const float* __restrict__ ptclds, u32* __restrict__ tab)
{
    const int i = blockIdx.x * 256 + threadIdx.x;
    if (i < P_) {
        auto q = [](float v) -> u32 {
            float x = (v + 6.f) * (1023.f / 12.f);
            x = fminf(fmaxf(x, 0.f), 1023.f);
            return (u32)(x + 0.5f);
        };
        tab[i] = q(ptclds[i]) | (q(ptclds[P_ + i]) << 10)
               | (q(ptclds[2 * P_ + i]) << 20);
    }
}

// R11: TLP-discrimination round. R10 post-mortem: unconditional gathers
// cost +30 us => divergent-gather line processing (~1.7 cyc/line) is a
// first-order cost; R7's masking stays. NEW evidence: warm replays (input
// fully L3-resident, ~0 HBM reads) run at the SAME 59.5 us => R7 is NOT
// HBM-bound. Remaining regimes: exposed latency (TLP-curable) vs VMEM-pipe
// throughput (not). This round: 1 px/thread, single variable vs R7 --
// same total bytes/lines/ops, but 2x waves (19200), half the per-wave
// critical path, no min-waves launch bound (HW free to pack 8 blocks/CU).
// Pre-committed read: ~50 us => latency regime, keep pushing TLP/overlap;
// ~60 us (null) => VMEM-pipe floor established.
__global__ __launch_bounds__(256) void compositor_kernel(
    const int*   __restrict__ frag,    // (B,K,H,W) int32
    const float* __restrict__ alpha,   // (B,K,H,W) f32
    const u32*   __restrict__ tab,     // (P) packed 3x10-bit table
    const float* __restrict__ im,      // (3,H,W) f32
    float*       __restrict__ out)     // (B,3,H,W) f32
{
    const int t = blockIdx.x * blockDim.x + threadIdx.x;   // [0, B_*HW)
    const int b = t / HW;
    const int p = t - b * HW;      // [0, HW)

    const int*   fb = frag  + (size_t)b * K_ * HW;
    const float* ab = alpha + (size_t)b * K_ * HW;

    // 1) stream loads, non-temporal (R2/R4 lesson: protect the table's
    //    L2 residency from the 157 MB stream)
    int fi[K_];
    #pragma unroll
    for (int k = 0; k < K_; ++k)
        fi[k] = __builtin_nontemporal_load(fb + (size_t)k * HW + p);
    float ai[K_];
    #pragma unroll
    for (int k = 0; k < K_; ++k)
        ai[k] = __builtin_nontemporal_load(ab + (size_t)k * HW + p);

    // 2) weights — pure VALU (bg skip + low-weight skip, EPS as R7)
    constexpr float EPS = 2.5e-3f;
    const bool bg = fi[0] < 0;
    float w[K_];
    {
        float T = 1.f;
        #pragma unroll
        for (int k = 0; k < K_; ++k) {
            const float a  = fi[k] >= 0 ? ai[k] : 0.0f;
            const float wk = a * T;  T *= (1.0f - a);
            w[k] = (!bg && wk > EPS) ? wk : 0.0f;
        }
    }

    // 3) exec-masked gathers (skipped lanes issue nothing — R10 proved
    //    each extra gather lane-lookup costs ~1.7 cycles of VMEM pipe)
    u32 pk[K_];
    #pragma unroll
    for (int k = 0; k < K_; ++k) {
        pk[k] = 0;
        if (w[k] > 0.0f) pk[k] = tab[fi[k]];
    }

    // 4) decode + accumulate (w==0 lanes: dummy decode x 0 -> exact)
    constexpr float S = 12.f / 1023.f;
    float r = 0.f, g = 0.f, bl = 0.f;
    #pragma unroll
    for (int k = 0; k < K_; ++k) {
        r  += w[k] * ((float)( pk[k]        & 1023u) * S - 6.f);
        g  += w[k] * ((float)((pk[k] >> 10) & 1023u) * S - 6.f);
        bl += w[k] * ((float)((pk[k] >> 20) & 1023u) * S - 6.f);
    }

    // 5) background override + non-temporal coalesced stores
    const size_t ob = (size_t)b * 3 * HW;
    const float o0 = bg ? im[p]          : r;
    const float o1 = bg ? im[HW + p]     : g;
    const float o2 = bg ? im[2 * HW + p] : bl;
    __builtin_nontemporal_store(o0, out + ob + p);
    __builtin_nontemporal_store(o1, out + ob + HW + p);
    __builtin_nontemporal_store(o2, out + ob + 2 * HW + p);
}

extern "C" void kernel_launch(void* const* d_in, const int* in_sizes, int n_in,
                              void* d_out, int out_size, void* d_ws, size_t ws_size,
                              hipStream_t stream) {
    const int*   frag   = (const int*)  d_in[0];
    const float* alpha  = (const float*)d_in[1];
    const float* ptclds = (const float*)d_in[2];
    const float* im     = (const float*)d_in[3];
    float*       out    = (float*)d_out;

    u32* tab = (u32*)d_ws;  // 800 KB < ws_size
    build_table<<<(P_ + 255) / 256, 256, 0, stream>>>(ptclds, tab);

    const int total_threads = B_ * HW;   // 1,228,800 (1 px/thread)
    compositor_kernel<<<total_threads / 256, 256, 0, stream>>>(
        frag, alpha, tab, im, out);
}